// Round 3
// baseline (347.399 us; speedup 1.0000x reference)
//
#include <hip/hip_runtime.h>

#define B_N 32
#define C_N 256
#define HW_N 4096
#define K_N 64
#define NT 32              // positions per subtile
#define SUBT 8             // subtiles per block -> 256 positions/block
#define NTHREADS 512
#define NBLOCKS 512        // 32 batches x 16 chunks
#define XROW 40            // padded row (u16 units) for x_s: stride 80B = 20 banks (coprime-ish)

typedef __attribute__((ext_vector_type(8))) short short8;
typedef __attribute__((ext_vector_type(4))) unsigned short ushort4v;
typedef __attribute__((ext_vector_type(4))) float f32x4;

__device__ __forceinline__ unsigned short f2bf(float f) {
    unsigned int u = __builtin_bit_cast(unsigned int, f);
    u = (u + 0x7FFFu + ((u >> 16) & 1u)) >> 16;   // RNE
    return (unsigned short)u;
}

// xT_s [NT][C] c-innermost; XOR swizzle: mm1 A-frag reads (lanes vary n&15) and
// staging transpose-writes both land <=2-way
__device__ __forceinline__ int xts_idx(int n, int c) {
    int sw = (n & 7) ^ ((n >> 3) & 3);
    return (n * C_N + c) ^ (sw << 3);
}
// thT_s [K][NT] n-innermost; swizzle spreads mm2 A-frag reads (lanes vary k&15)
__device__ __forceinline__ int tht_idx(int k, int n) {
    int sw = (k & 3) ^ ((k >> 2) & 3);
    return (k * NT + n) ^ (sw << 3);
}

__launch_bounds__(NTHREADS, 6)
__global__ void se_main_kernel(const float* __restrict__ x,
                               const float* __restrict__ clusters,
                               const float* __restrict__ scale,
                               float* __restrict__ ws_enc,
                               float* __restrict__ ws_ts) {
    __shared__ unsigned short x_s[C_N * XROW];    // 20480 B  [C][40] n-innermost, pad-40
    __shared__ unsigned short xT_s[NT * C_N];     // 16384 B  [NT][C] c-innermost, swizzled
    __shared__ float xcT_s[K_N * (NT + 1)];       //  8448 B  [K][NT+1]
    __shared__ unsigned short thT_s[K_N * NT];    //  4096 B  [K][NT] swizzled
    __shared__ float xsqp_s[8 * NT];              //  1024 B  per-wave x_sq partials
    __shared__ float csq_s[K_N];                  //   256 B
    __shared__ float scl2_s[K_N];                 //   256 B   total 50944 B -> 3 blocks/CU
    // softmax (max,sum) partials aliased onto xT_s (consumed before next staging write)
    float* msm_s = (float*)xT_s;                  // 16*NT floats
    float* mss_s = ((float*)xT_s) + 16 * NT;      // 16*NT floats

    const int tid = threadIdx.x;
    const int w = tid >> 6;         // wave 0..7
    const int l = tid & 63;
    const int gid = blockIdx.x;
    const int b = gid >> 4;
    const int chunk = gid & 15;
    const int r16 = l & 15, g16 = l >> 4;
    const int u = l >> 3;           // staging c sub-row
    const int ng = l & 7;           // staging n-group (4 consecutive n)
    const int n32 = l & 31;         // softmax position
    const int kq = w * 2 + (l >> 5);// softmax k-quad group 0..15

    // ---- c_sq and scale*log2(e), fp32 exact ----
    if (tid < K_N) {
        const float4* cr = (const float4*)(clusters + tid * C_N);
        float ss = 0.f;
        #pragma unroll 8
        for (int i = 0; i < C_N / 4; ++i) {
            float4 v = cr[i];
            ss += v.x * v.x + v.y * v.y + v.z * v.z + v.w * v.w;
        }
        csq_s[tid] = ss;
        scl2_s[tid] = scale[tid] * 1.4426950408889634f;
    }

    // ---- mm1 clusters B-fragments in registers: wave w owns k-tile kt, n-tile nt1 ----
    const int kt = w >> 1;          // 0..3
    const int nt1 = w & 1;          // 0..1
    short8 cb[8];
    #pragma unroll
    for (int st = 0; st < 8; ++st) {
        int k = kt * 16 + r16;
        int c0 = st * 32 + g16 * 8;
        const float* p = clusters + k * C_N + c0;
        short8 v;
        #pragma unroll
        for (int j = 0; j < 8; ++j) v[j] = (short)f2bf(p[j]);
        cb[st] = v;
    }

    // mm2: enc(K x C); wave w owns c-tiles {2w,2w+1}, all 4 k-tiles
    const int ct0 = w * 2;
    f32x4 acc[4][2];
    #pragma unroll
    for (int a = 0; a < 4; ++a)
        #pragma unroll
        for (int cc = 0; cc < 2; ++cc) acc[a][cc] = (f32x4)0.f;
    float ts_reg[4] = {0.f, 0.f, 0.f, 0.f};

    // ---- prefetch subtile 0 into registers ----
    const size_t xbase = (size_t)b * C_N * HW_N + chunk * (SUBT * NT);
    float4 pva[4];
    #pragma unroll
    for (int p = 0; p < 4; ++p)
        pva[p] = *(const float4*)(x + xbase + (size_t)(w * 8 + u + p * 64) * HW_N + ng * 4);

    for (int s = 0; s < SUBT; ++s) {
        __syncthreads();  // BAR0: x_s/xT_s/thT free (prev mm2 done)

        // ---- convert prefetched regs -> bf16 LDS (both layouts), x_sq partials ----
        float xsq4[4] = {0.f, 0.f, 0.f, 0.f};
        #pragma unroll
        for (int p = 0; p < 4; ++p) {
            int c = w * 8 + u + p * 64;
            float v0 = pva[p].x, v1 = pva[p].y, v2 = pva[p].z, v3 = pva[p].w;
            xsq4[0] += v0 * v0; xsq4[1] += v1 * v1;
            xsq4[2] += v2 * v2; xsq4[3] += v3 * v3;
            unsigned short b0 = f2bf(v0), b1 = f2bf(v1), b2 = f2bf(v2), b3 = f2bf(v3);
            ushort4v pk = {b0, b1, b2, b3};
            *(ushort4v*)&x_s[c * XROW + ng * 4] = pk;       // b64 write, ~2-way max
            xT_s[xts_idx(ng * 4 + 0, c)] = b0;              // swizzled transpose
            xT_s[xts_idx(ng * 4 + 1, c)] = b1;
            xT_s[xts_idx(ng * 4 + 2, c)] = b2;
            xT_s[xts_idx(ng * 4 + 3, c)] = b3;
        }
        // ---- issue next subtile's loads NOW; latency hides under mm1+softmax+mm2 ----
        if (s + 1 < SUBT) {
            #pragma unroll
            for (int p = 0; p < 4; ++p)
                pva[p] = *(const float4*)(x + xbase + (size_t)(w * 8 + u + p * 64) * HW_N
                                          + (s + 1) * NT + ng * 4);
        }
        // x_sq reduce over u (lane bits 3..5), fp32 exact
        #pragma unroll
        for (int i = 0; i < 4; ++i) {
            float t = xsq4[i];
            t += __shfl_xor(t, 8, 64);
            t += __shfl_xor(t, 16, 64);
            t += __shfl_xor(t, 32, 64);
            xsq4[i] = t;
        }
        if (u == 0) {
            #pragma unroll
            for (int i = 0; i < 4; ++i) xsqp_s[w * NT + ng * 4 + i] = xsq4[i];
        }
        __syncthreads(); // BAR1: xT_s + xsq partials ready

        // ---- mm1: one 16x16 tile per wave, D[n][k] ----
        {
            f32x4 a0 = (f32x4)0.f;
            #pragma unroll
            for (int st = 0; st < 8; ++st) {
                short8 af = *(const short8*)&xT_s[xts_idx(nt1 * 16 + r16, st * 32 + g16 * 8)];
                a0 = __builtin_amdgcn_mfma_f32_16x16x32_bf16(af, cb[st], a0, 0, 0, 0);
            }
            #pragma unroll
            for (int rr = 0; rr < 4; ++rr)
                xcT_s[(kt * 16 + r16) * (NT + 1) + nt1 * 16 + g16 * 4 + rr] = a0[rr];
        }
        __syncthreads(); // BAR2: xcT ready

        // ---- softmax: thread owns (n=n32, 4 k's of group kq), single partial barrier ----
        float xsq = 0.f;
        #pragma unroll
        for (int ww = 0; ww < 8; ++ww) xsq += xsqp_s[ww * NT + n32];
        float lg[4], m8 = -1e30f;
        #pragma unroll
        for (int j = 0; j < 4; ++j) {
            int k = kq * 4 + j;
            float xc = xcT_s[k * (NT + 1) + n32];
            lg[j] = scl2_s[k] * (xsq - 2.f * xc + csq_s[k]);   // log2 domain
            m8 = fmaxf(m8, lg[j]);
        }
        float e4[4], s8 = 0.f;
        #pragma unroll
        for (int j = 0; j < 4; ++j) { e4[j] = exp2f(lg[j] - m8); s8 += e4[j]; }
        msm_s[kq * NT + n32] = m8;
        mss_s[kq * NT + n32] = s8;
        __syncthreads(); // BAR3: (max,sum) partials ready

        float mv[16], M = -1e30f;
        #pragma unroll
        for (int g = 0; g < 16; ++g) {
            mv[g] = msm_s[g * NT + n32];
            M = fmaxf(M, mv[g]);
        }
        float S = 0.f;
        #pragma unroll
        for (int g = 0; g < 16; ++g) S += mss_s[g * NT + n32] * exp2f(mv[g] - M);
        float fsc = __fdividef(exp2f(m8 - M), S);
        #pragma unroll
        for (int j = 0; j < 4; ++j) {
            float th = e4[j] * fsc;
            thT_s[tht_idx(kq * 4 + j, n32)] = f2bf(th);
            float t = th;                       // theta_sum over n (32 lanes)
            t += __shfl_xor(t, 1, 64);
            t += __shfl_xor(t, 2, 64);
            t += __shfl_xor(t, 4, 64);
            t += __shfl_xor(t, 8, 64);
            t += __shfl_xor(t, 16, 64);
            ts_reg[j] += t;
        }
        __syncthreads(); // BAR4: thT ready

        // ---- mm2: acc[k-tile][c-tile] += thetaT * xf (single K=32 step) ----
        short8 av[4];
        #pragma unroll
        for (int k2 = 0; k2 < 4; ++k2)
            av[k2] = *(const short8*)&thT_s[tht_idx(k2 * 16 + r16, g16 * 8)];
        #pragma unroll
        for (int cc = 0; cc < 2; ++cc) {
            short8 bv = *(const short8*)&x_s[((ct0 + cc) * 16 + r16) * XROW + g16 * 8];
            #pragma unroll
            for (int k2 = 0; k2 < 4; ++k2)
                acc[k2][cc] = __builtin_amdgcn_mfma_f32_16x16x32_bf16(av[k2], bv, acc[k2][cc], 0, 0, 0);
        }
    }

    // ---- write per-block partials ----
    float* eb = ws_enc + (size_t)gid * (K_N * C_N);
    #pragma unroll
    for (int k2 = 0; k2 < 4; ++k2) {
        #pragma unroll
        for (int cc = 0; cc < 2; ++cc) {
            int c = (ct0 + cc) * 16 + r16;
            #pragma unroll
            for (int rr = 0; rr < 4; ++rr) {
                int k = k2 * 16 + g16 * 4 + rr;
                eb[k * C_N + c] = acc[k2][cc][rr];
            }
        }
    }
    if ((l & 31) == 0) {
        #pragma unroll
        for (int j = 0; j < 4; ++j) ws_ts[gid * K_N + kq * 4 + j] = ts_reg[j];
    }
}

__global__ void se_reduce_kernel(const float* __restrict__ ws_enc,
                                 const float* __restrict__ ws_ts,
                                 const float* __restrict__ clusters,
                                 float* __restrict__ out) {
    int tid = blockIdx.x * 256 + threadIdx.x;   // 131072 threads: (b,k,c4)
    int c4 = tid & 63;
    int k = (tid >> 6) & 63;
    int b = tid >> 12;
    float4 a = {0.f, 0.f, 0.f, 0.f};
    size_t base = (size_t)(b * 16) * (K_N * C_N) + k * C_N + c4 * 4;
    #pragma unroll
    for (int p = 0; p < 16; ++p) {
        float4 v = *(const float4*)(ws_enc + base + (size_t)p * (K_N * C_N));
        a.x += v.x; a.y += v.y; a.z += v.z; a.w += v.w;
    }
    float ts = 0.f;
    #pragma unroll
    for (int p = 0; p < 16; ++p) ts += ws_ts[(b * 16 + p) * K_N + k];
    float4 cl = *(const float4*)(clusters + k * C_N + c4 * 4);
    float4 o;
    o.x = a.x - ts * cl.x;
    o.y = a.y - ts * cl.y;
    o.z = a.z - ts * cl.z;
    o.w = a.w - ts * cl.w;
    *(float4*)(out + (size_t)(b * K_N + k) * C_N + c4 * 4) = o;
}

extern "C" void kernel_launch(void* const* d_in, const int* in_sizes, int n_in,
                              void* d_out, int out_size, void* d_ws, size_t ws_size,
                              hipStream_t stream) {
    const float* x        = (const float*)d_in[0];
    const float* clusters = (const float*)d_in[1];
    const float* scale    = (const float*)d_in[2];
    float* out    = (float*)d_out;
    float* ws_enc = (float*)d_ws;                                  // 512*64*256 f32 = 32 MB
    float* ws_ts  = ws_enc + (size_t)NBLOCKS * K_N * C_N;          // + 512*64 f32

    se_main_kernel<<<NBLOCKS, NTHREADS, 0, stream>>>(x, clusters, scale, ws_enc, ws_ts);
    se_reduce_kernel<<<(B_N * K_N * 64) / 256, 256, 0, stream>>>(ws_enc, ws_ts, clusters, out);
}

// Round 5
// 277.354 us; speedup vs baseline: 1.2525x; 1.2525x over previous
//
#include <hip/hip_runtime.h>

#define B_N 32
#define C_N 256
#define HW_N 4096
#define K_N 64
#define NT 32              // positions per subtile
#define SUBT 8             // subtiles per block -> 256 positions/block
#define NTHREADS 512
#define NBLOCKS 512        // 32 batches x 16 chunks -> 2 blocks/CU
#define XROW 40            // padded row (u16 units) for x_s

typedef __attribute__((ext_vector_type(8))) short short8;
typedef __attribute__((ext_vector_type(4))) unsigned short ushort4v;
typedef __attribute__((ext_vector_type(4))) float f32x4;

__device__ __forceinline__ unsigned short f2bf(float f) {
    unsigned int u = __builtin_bit_cast(unsigned int, f);
    u = (u + 0x7FFFu + ((u >> 16) & 1u)) >> 16;   // RNE
    return (unsigned short)u;
}

// xT_s [NT][C] c-innermost; XOR swizzle: mm1 A-frag reads and staging
// transpose-writes both land <=2-way
__device__ __forceinline__ int xts_idx(int n, int c) {
    int sw = (n & 7) ^ ((n >> 3) & 3);
    return (n * C_N + c) ^ (sw << 3);
}
// thT_s [K][NT] n-innermost; round-1-verified swizzle. Mask hits n-bits 3..4
// ONLY -> b128 fragment reads stay 16B-aligned + contiguous (round-4's bit-2
// XOR variant produced misaligned ds_read_b128 -> NaN garbage).
__device__ __forceinline__ int tht_idx(int k, int n) {
    int sw = (k & 3) ^ ((k >> 2) & 3);
    return (k * NT + n) ^ (sw << 3);
}

__launch_bounds__(NTHREADS, 4)   // VGPR cap 128 — (512,6) forced cap ~85 -> catastrophic spill (round 3)
__global__ void se_main_kernel(const float* __restrict__ x,
                               const float* __restrict__ clusters,
                               const float* __restrict__ scale,
                               float* __restrict__ ws_enc,
                               float* __restrict__ ws_ts) {
    __shared__ unsigned short x_s[C_N * XROW];    // 20480 B  [C][40] n-innermost, pad-40
    __shared__ unsigned short xT_s[NT * C_N];     // 16384 B  [NT][C] c-innermost, swizzled
    __shared__ float xcT_s[K_N * (NT + 1)];       //  8448 B  [K][NT+1]
    __shared__ unsigned short thT_s[K_N * NT];    //  4096 B  [K][NT] swizzled
    __shared__ float xsqp_s[8 * NT];              //  1024 B  per-wave x_sq partials
    __shared__ float csq_s[K_N];                  //   256 B
    __shared__ float scl2_s[K_N];                 //   256 B   total 50944 B

    const int tid = threadIdx.x;
    const int w = tid >> 6;         // wave 0..7
    const int l = tid & 63;
    const int gid = blockIdx.x;
    const int b = gid >> 4;
    const int chunk = gid & 15;
    const int r16 = l & 15, g16 = l >> 4;
    const int u = l >> 3;           // staging c sub-row
    const int ng = l & 7;           // staging n-group (4 consecutive n)
    // softmax mapping: 16 lanes (r16) per position, each lane 4 k's
    const int sm_n = w * 4 + g16;   // position 0..31

    // ---- c_sq and scale*log2(e), fp32 exact ----
    if (tid < K_N) {
        const float4* cr = (const float4*)(clusters + tid * C_N);
        float ss = 0.f;
        #pragma unroll 8
        for (int i = 0; i < C_N / 4; ++i) {
            float4 v = cr[i];
            ss += v.x * v.x + v.y * v.y + v.z * v.z + v.w * v.w;
        }
        csq_s[tid] = ss;
        scl2_s[tid] = scale[tid] * 1.4426950408889634f;
    }

    // ---- mm1 clusters B-fragments in registers: wave w owns k-tile kt, n-tile nt1 ----
    const int kt = w >> 1;          // 0..3
    const int nt1 = w & 1;          // 0..1
    short8 cb[8];
    #pragma unroll
    for (int st = 0; st < 8; ++st) {
        int k = kt * 16 + r16;
        int c0 = st * 32 + g16 * 8;
        const float* p = clusters + k * C_N + c0;
        short8 v;
        #pragma unroll
        for (int j = 0; j < 8; ++j) v[j] = (short)f2bf(p[j]);
        cb[st] = v;
    }

    // mm2: enc(K x C); wave w owns c-tiles {2w,2w+1}, all 4 k-tiles
    const int ct0 = w * 2;
    f32x4 acc[4][2];
    #pragma unroll
    for (int a = 0; a < 4; ++a)
        #pragma unroll
        for (int cc = 0; cc < 2; ++cc) acc[a][cc] = (f32x4)0.f;
    float ts_acc[4] = {0.f, 0.f, 0.f, 0.f};   // per-thread theta partials (k=r16*4+j, own positions)

    // ---- prefetch subtile 0 into registers ----
    const size_t xbase = (size_t)b * C_N * HW_N + chunk * (SUBT * NT);
    float4 pva[4];
    #pragma unroll
    for (int p = 0; p < 4; ++p)
        pva[p] = *(const float4*)(x + xbase + (size_t)(w * 8 + u + p * 64) * HW_N + ng * 4);

    for (int s = 0; s < SUBT; ++s) {
        __syncthreads();  // BAR0: x_s/xT_s/thT free (prev mm2 done)

        // ---- convert prefetched regs -> bf16 LDS (both layouts), x_sq partials ----
        float xsq4[4] = {0.f, 0.f, 0.f, 0.f};
        #pragma unroll
        for (int p = 0; p < 4; ++p) {
            int c = w * 8 + u + p * 64;
            float v0 = pva[p].x, v1 = pva[p].y, v2 = pva[p].z, v3 = pva[p].w;
            xsq4[0] += v0 * v0; xsq4[1] += v1 * v1;
            xsq4[2] += v2 * v2; xsq4[3] += v3 * v3;
            unsigned short b0 = f2bf(v0), b1 = f2bf(v1), b2 = f2bf(v2), b3 = f2bf(v3);
            ushort4v pk = {b0, b1, b2, b3};
            *(ushort4v*)&x_s[c * XROW + ng * 4] = pk;       // b64 write, ~2-way max
            xT_s[xts_idx(ng * 4 + 0, c)] = b0;              // swizzled transpose
            xT_s[xts_idx(ng * 4 + 1, c)] = b1;
            xT_s[xts_idx(ng * 4 + 2, c)] = b2;
            xT_s[xts_idx(ng * 4 + 3, c)] = b3;
        }
        // ---- issue next subtile's loads NOW; latency hides under mm1+softmax+mm2 ----
        if (s + 1 < SUBT) {
            #pragma unroll
            for (int p = 0; p < 4; ++p)
                pva[p] = *(const float4*)(x + xbase + (size_t)(w * 8 + u + p * 64) * HW_N
                                          + (s + 1) * NT + ng * 4);
        }
        // x_sq reduce over u (lane bits 3..5), fp32 exact
        #pragma unroll
        for (int i = 0; i < 4; ++i) {
            float t = xsq4[i];
            t += __shfl_xor(t, 8, 64);
            t += __shfl_xor(t, 16, 64);
            t += __shfl_xor(t, 32, 64);
            xsq4[i] = t;
        }
        if (u == 0) {
            #pragma unroll
            for (int i = 0; i < 4; ++i) xsqp_s[w * NT + ng * 4 + i] = xsq4[i];
        }
        __syncthreads(); // BAR1: xT_s + xsq partials ready

        // ---- mm1: one 16x16 tile per wave, D[n][k] ----
        {
            f32x4 a0 = (f32x4)0.f;
            #pragma unroll
            for (int st = 0; st < 8; ++st) {
                short8 af = *(const short8*)&xT_s[xts_idx(nt1 * 16 + r16, st * 32 + g16 * 8)];
                a0 = __builtin_amdgcn_mfma_f32_16x16x32_bf16(af, cb[st], a0, 0, 0, 0);
            }
            #pragma unroll
            for (int rr = 0; rr < 4; ++rr)
                xcT_s[(kt * 16 + r16) * (NT + 1) + nt1 * 16 + g16 * 4 + rr] = a0[rr];
        }
        __syncthreads(); // BAR2: xcT ready

        // ---- softmax, fully in-wave: position sm_n, lane r16 owns k=r16*4+j ----
        float xsq = 0.f;
        #pragma unroll
        for (int ww = 0; ww < 8; ++ww) xsq += xsqp_s[ww * NT + sm_n];
        float lg[4], m8 = -1e30f;
        #pragma unroll
        for (int j = 0; j < 4; ++j) {
            int k = r16 * 4 + j;
            float xc = xcT_s[k * (NT + 1) + sm_n];
            lg[j] = scl2_s[k] * (xsq - 2.f * xc + csq_s[k]);   // log2 domain
            m8 = fmaxf(m8, lg[j]);
        }
        // global max over 64 k = 16-lane butterfly (lane bits 0-3)
        m8 = fmaxf(m8, __shfl_xor(m8, 1, 64));
        m8 = fmaxf(m8, __shfl_xor(m8, 2, 64));
        m8 = fmaxf(m8, __shfl_xor(m8, 4, 64));
        m8 = fmaxf(m8, __shfl_xor(m8, 8, 64));
        float e4[4], s8 = 0.f;
        #pragma unroll
        for (int j = 0; j < 4; ++j) { e4[j] = exp2f(lg[j] - m8); s8 += e4[j]; }
        s8 += __shfl_xor(s8, 1, 64);
        s8 += __shfl_xor(s8, 2, 64);
        s8 += __shfl_xor(s8, 4, 64);
        s8 += __shfl_xor(s8, 8, 64);
        float fsc = __fdividef(1.0f, s8);
        #pragma unroll
        for (int j = 0; j < 4; ++j) {
            float th = e4[j] * fsc;
            thT_s[tht_idx(r16 * 4 + j, sm_n)] = f2bf(th);
            ts_acc[j] += th;                 // deferred theta_sum (reduced once at end)
        }
        __syncthreads(); // BAR3: thT ready

        // ---- mm2: acc[k-tile][c-tile] += thetaT * xf (single K=32 step) ----
        short8 av[4];
        #pragma unroll
        for (int k2 = 0; k2 < 4; ++k2)
            av[k2] = *(const short8*)&thT_s[tht_idx(k2 * 16 + r16, g16 * 8)];
        #pragma unroll
        for (int cc = 0; cc < 2; ++cc) {
            short8 bv = *(const short8*)&x_s[((ct0 + cc) * 16 + r16) * XROW + g16 * 8];
            #pragma unroll
            for (int k2 = 0; k2 < 4; ++k2)
                acc[k2][cc] = __builtin_amdgcn_mfma_f32_16x16x32_bf16(av[k2], bv, acc[k2][cc], 0, 0, 0);
        }
    }

    // ---- write per-block enc partials ----
    float* eb = ws_enc + (size_t)gid * (K_N * C_N);
    #pragma unroll
    for (int k2 = 0; k2 < 4; ++k2) {
        #pragma unroll
        for (int cc = 0; cc < 2; ++cc) {
            int c = (ct0 + cc) * 16 + r16;
            #pragma unroll
            for (int rr = 0; rr < 4; ++rr) {
                int k = k2 * 16 + g16 * 4 + rr;
                eb[k * C_N + c] = acc[k2][cc][rr];
            }
        }
    }
    // ---- theta_sum: per-thread partials -> LDS (reuse xcT_s) -> 64-thread reduce ----
    #pragma unroll
    for (int j = 0; j < 4; ++j)
        xcT_s[(r16 * 4 + j) * (NT + 1) + sm_n] = ts_acc[j];
    __syncthreads();
    if (tid < K_N) {
        float ts = 0.f;
        #pragma unroll 8
        for (int n = 0; n < NT; ++n) ts += xcT_s[tid * (NT + 1) + n];
        ws_ts[gid * K_N + tid] = ts;
    }
}

__global__ void se_reduce_kernel(const float* __restrict__ ws_enc,
                                 const float* __restrict__ ws_ts,
                                 const float* __restrict__ clusters,
                                 float* __restrict__ out) {
    int tid = blockIdx.x * 256 + threadIdx.x;   // 131072 threads: (b,k,c4)
    int c4 = tid & 63;
    int k = (tid >> 6) & 63;
    int b = tid >> 12;
    float4 a = {0.f, 0.f, 0.f, 0.f};
    size_t base = (size_t)(b * 16) * (K_N * C_N) + k * C_N + c4 * 4;
    #pragma unroll
    for (int p = 0; p < 16; ++p) {
        float4 v = *(const float4*)(ws_enc + base + (size_t)p * (K_N * C_N));
        a.x += v.x; a.y += v.y; a.z += v.z; a.w += v.w;
    }
    float ts = 0.f;
    #pragma unroll
    for (int p = 0; p < 16; ++p) ts += ws_ts[(b * 16 + p) * K_N + k];
    float4 cl = *(const float4*)(clusters + k * C_N + c4 * 4);
    float4 o;
    o.x = a.x - ts * cl.x;
    o.y = a.y - ts * cl.y;
    o.z = a.z - ts * cl.z;
    o.w = a.w - ts * cl.w;
    *(float4*)(out + (size_t)(b * K_N + k) * C_N + c4 * 4) = o;
}

extern "C" void kernel_launch(void* const* d_in, const int* in_sizes, int n_in,
                              void* d_out, int out_size, void* d_ws, size_t ws_size,
                              hipStream_t stream) {
    const float* x        = (const float*)d_in[0];
    const float* clusters = (const float*)d_in[1];
    const float* scale    = (const float*)d_in[2];
    float* out    = (float*)d_out;
    float* ws_enc = (float*)d_ws;                                  // 512*64*256 f32 = 32 MB
    float* ws_ts  = ws_enc + (size_t)NBLOCKS * K_N * C_N;          // + 512*64 f32

    se_main_kernel<<<NBLOCKS, NTHREADS, 0, stream>>>(x, clusters, scale, ws_enc, ws_ts);
    se_reduce_kernel<<<(B_N * K_N * 64) / 256, 256, 0, stream>>>(ws_enc, ws_ts, clusters, out);
}

// Round 6
// 272.453 us; speedup vs baseline: 1.2751x; 1.0180x over previous
//
#include <hip/hip_runtime.h>

#define B_N 32
#define C_N 256
#define HW_N 4096
#define K_N 64
#define NT 32              // positions per subtile
#define SUBT 8             // subtiles per block -> 256 positions/block
#define NTHREADS 512
#define NBLOCKS 512        // 32 batches x 16 chunks -> 2 blocks/CU
#define XROW 40            // padded row (u16 units) for x_s

typedef __attribute__((ext_vector_type(8))) short short8;
typedef __attribute__((ext_vector_type(4))) unsigned short ushort4v;
typedef __attribute__((ext_vector_type(4))) float f32x4;

__device__ __forceinline__ unsigned short f2bf(float f) {
    unsigned int u = __builtin_bit_cast(unsigned int, f);
    u = (u + 0x7FFFu + ((u >> 16) & 1u)) >> 16;   // RNE
    return (unsigned short)u;
}

// xT_s [NT][C] c-innermost; XOR swizzle: mm1 A-frag reads and staging
// transpose-writes both land <=2-way
__device__ __forceinline__ int xts_idx(int n, int c) {
    int sw = (n & 7) ^ ((n >> 3) & 3);
    return (n * C_N + c) ^ (sw << 3);
}
// thT_s [K][NT] n-innermost; mask hits n-bits 3..4 ONLY -> b128 fragment
// reads stay 16B-aligned + contiguous (bit-2 XOR variant NaN'd in round 4).
__device__ __forceinline__ int tht_idx(int k, int n) {
    int sw = (k & 3) ^ ((k >> 2) & 3);
    return (k * NT + n) ^ (sw << 3);
}

// waves_per_eu(4,4): pin EXACTLY 4 waves/SIMD -> VGPR budget 128, no spill.
// (512,4) launch_bounds alone let the allocator chase the 8-wave tier at
// VGPR=64 -> ~50 spilled regs, +35MB scratch writes, 139us (round 5).
__global__ __launch_bounds__(NTHREADS)
__attribute__((amdgpu_waves_per_eu(4, 4)))
void se_main_kernel(const float* __restrict__ x,
                    const float* __restrict__ clusters,
                    const float* __restrict__ scale,
                    float* __restrict__ ws_enc,
                    float* __restrict__ ws_ts) {
    __shared__ unsigned short x_s[C_N * XROW];    // 20480 B  [C][40] n-innermost, pad-40
    __shared__ unsigned short xT_s[NT * C_N];     // 16384 B  [NT][C] c-innermost, swizzled
    __shared__ float xcT_s[K_N * (NT + 1)];       //  8448 B  [K][NT+1]
    __shared__ unsigned short thT_s[K_N * NT];    //  4096 B  [K][NT] swizzled
    __shared__ float xsqp_s[8 * NT];              //  1024 B  per-wave x_sq partials
    __shared__ float csq_s[K_N];                  //   256 B
    __shared__ float scl2_s[K_N];                 //   256 B   total 50944 B

    const int tid = threadIdx.x;
    const int w = tid >> 6;         // wave 0..7
    const int l = tid & 63;
    const int gid = blockIdx.x;
    const int b = gid >> 4;
    const int chunk = gid & 15;
    const int r16 = l & 15, g16 = l >> 4;
    const int u = l >> 3;           // staging c sub-row
    const int ng = l & 7;           // staging n-group (4 consecutive n)
    // softmax mapping: 16 lanes (r16) per position, each lane 4 k's
    const int sm_n = w * 4 + g16;   // position 0..31

    // ---- c_sq and scale*log2(e), fp32 exact ----
    if (tid < K_N) {
        const float4* cr = (const float4*)(clusters + tid * C_N);
        float ss = 0.f;
        #pragma unroll 8
        for (int i = 0; i < C_N / 4; ++i) {
            float4 v = cr[i];
            ss += v.x * v.x + v.y * v.y + v.z * v.z + v.w * v.w;
        }
        csq_s[tid] = ss;
        scl2_s[tid] = scale[tid] * 1.4426950408889634f;
    }

    // ---- mm1 clusters B-fragments in registers: wave w owns k-tile kt, n-tile nt1 ----
    const int kt = w >> 1;          // 0..3
    const int nt1 = w & 1;          // 0..1
    short8 cb[8];
    #pragma unroll
    for (int st = 0; st < 8; ++st) {
        int k = kt * 16 + r16;
        int c0 = st * 32 + g16 * 8;
        const float* p = clusters + k * C_N + c0;
        short8 v;
        #pragma unroll
        for (int j = 0; j < 8; ++j) v[j] = (short)f2bf(p[j]);
        cb[st] = v;
    }

    // mm2: enc(K x C); wave w owns c-tiles {2w,2w+1}, all 4 k-tiles
    const int ct0 = w * 2;
    f32x4 acc[4][2];
    #pragma unroll
    for (int a = 0; a < 4; ++a)
        #pragma unroll
        for (int cc = 0; cc < 2; ++cc) acc[a][cc] = (f32x4)0.f;
    float ts_acc[4] = {0.f, 0.f, 0.f, 0.f};   // per-thread theta partials (k=r16*4+j, own positions)

    // ---- prefetch subtile 0 into registers ----
    const size_t xbase = (size_t)b * C_N * HW_N + chunk * (SUBT * NT);
    float4 pva[4];
    #pragma unroll
    for (int p = 0; p < 4; ++p)
        pva[p] = *(const float4*)(x + xbase + (size_t)(w * 8 + u + p * 64) * HW_N + ng * 4);

    for (int s = 0; s < SUBT; ++s) {
        __syncthreads();  // BAR0: x_s/xT_s/thT free (prev mm2 done)

        // ---- convert prefetched regs -> bf16 LDS (both layouts), x_sq partials ----
        float xsq4[4] = {0.f, 0.f, 0.f, 0.f};
        #pragma unroll
        for (int p = 0; p < 4; ++p) {
            int c = w * 8 + u + p * 64;
            float v0 = pva[p].x, v1 = pva[p].y, v2 = pva[p].z, v3 = pva[p].w;
            xsq4[0] += v0 * v0; xsq4[1] += v1 * v1;
            xsq4[2] += v2 * v2; xsq4[3] += v3 * v3;
            unsigned short b0 = f2bf(v0), b1 = f2bf(v1), b2 = f2bf(v2), b3 = f2bf(v3);
            ushort4v pk = {b0, b1, b2, b3};
            *(ushort4v*)&x_s[c * XROW + ng * 4] = pk;       // b64 write, ~2-way max
            xT_s[xts_idx(ng * 4 + 0, c)] = b0;              // swizzled transpose
            xT_s[xts_idx(ng * 4 + 1, c)] = b1;
            xT_s[xts_idx(ng * 4 + 2, c)] = b2;
            xT_s[xts_idx(ng * 4 + 3, c)] = b3;
        }
        // ---- issue next subtile's loads NOW; latency hides under mm1+softmax+mm2 ----
        if (s + 1 < SUBT) {
            #pragma unroll
            for (int p = 0; p < 4; ++p)
                pva[p] = *(const float4*)(x + xbase + (size_t)(w * 8 + u + p * 64) * HW_N
                                          + (s + 1) * NT + ng * 4);
        }
        // x_sq reduce over u (lane bits 3..5), fp32 exact
        #pragma unroll
        for (int i = 0; i < 4; ++i) {
            float t = xsq4[i];
            t += __shfl_xor(t, 8, 64);
            t += __shfl_xor(t, 16, 64);
            t += __shfl_xor(t, 32, 64);
            xsq4[i] = t;
        }
        if (u == 0) {
            #pragma unroll
            for (int i = 0; i < 4; ++i) xsqp_s[w * NT + ng * 4 + i] = xsq4[i];
        }
        __syncthreads(); // BAR1: xT_s + xsq partials ready

        // ---- mm1: one 16x16 tile per wave, D[n][k] ----
        {
            f32x4 a0 = (f32x4)0.f;
            #pragma unroll
            for (int st = 0; st < 8; ++st) {
                short8 af = *(const short8*)&xT_s[xts_idx(nt1 * 16 + r16, st * 32 + g16 * 8)];
                a0 = __builtin_amdgcn_mfma_f32_16x16x32_bf16(af, cb[st], a0, 0, 0, 0);
            }
            #pragma unroll
            for (int rr = 0; rr < 4; ++rr)
                xcT_s[(kt * 16 + r16) * (NT + 1) + nt1 * 16 + g16 * 4 + rr] = a0[rr];
        }
        __syncthreads(); // BAR2: xcT ready

        // ---- softmax, fully in-wave: position sm_n, lane r16 owns k=r16*4+j ----
        float xsq = 0.f;
        #pragma unroll
        for (int ww = 0; ww < 8; ++ww) xsq += xsqp_s[ww * NT + sm_n];
        float lg[4], m8 = -1e30f;
        #pragma unroll
        for (int j = 0; j < 4; ++j) {
            int k = r16 * 4 + j;
            float xc = xcT_s[k * (NT + 1) + sm_n];
            lg[j] = scl2_s[k] * (xsq - 2.f * xc + csq_s[k]);   // log2 domain
            m8 = fmaxf(m8, lg[j]);
        }
        // global max over 64 k = 16-lane butterfly (lane bits 0-3)
        m8 = fmaxf(m8, __shfl_xor(m8, 1, 64));
        m8 = fmaxf(m8, __shfl_xor(m8, 2, 64));
        m8 = fmaxf(m8, __shfl_xor(m8, 4, 64));
        m8 = fmaxf(m8, __shfl_xor(m8, 8, 64));
        float e4[4], s8 = 0.f;
        #pragma unroll
        for (int j = 0; j < 4; ++j) { e4[j] = exp2f(lg[j] - m8); s8 += e4[j]; }
        s8 += __shfl_xor(s8, 1, 64);
        s8 += __shfl_xor(s8, 2, 64);
        s8 += __shfl_xor(s8, 4, 64);
        s8 += __shfl_xor(s8, 8, 64);
        float fsc = __fdividef(1.0f, s8);
        #pragma unroll
        for (int j = 0; j < 4; ++j) {
            float th = e4[j] * fsc;
            thT_s[tht_idx(r16 * 4 + j, sm_n)] = f2bf(th);
            ts_acc[j] += th;                 // deferred theta_sum (reduced once at end)
        }
        __syncthreads(); // BAR3: thT ready

        // ---- mm2: acc[k-tile][c-tile] += thetaT * xf (single K=32 step) ----
        short8 av[4];
        #pragma unroll
        for (int k2 = 0; k2 < 4; ++k2)
            av[k2] = *(const short8*)&thT_s[tht_idx(k2 * 16 + r16, g16 * 8)];
        #pragma unroll
        for (int cc = 0; cc < 2; ++cc) {
            short8 bv = *(const short8*)&x_s[((ct0 + cc) * 16 + r16) * XROW + g16 * 8];
            #pragma unroll
            for (int k2 = 0; k2 < 4; ++k2)
                acc[k2][cc] = __builtin_amdgcn_mfma_f32_16x16x32_bf16(av[k2], bv, acc[k2][cc], 0, 0, 0);
        }
    }

    // ---- write per-block enc partials ----
    float* eb = ws_enc + (size_t)gid * (K_N * C_N);
    #pragma unroll
    for (int k2 = 0; k2 < 4; ++k2) {
        #pragma unroll
        for (int cc = 0; cc < 2; ++cc) {
            int c = (ct0 + cc) * 16 + r16;
            #pragma unroll
            for (int rr = 0; rr < 4; ++rr) {
                int k = k2 * 16 + g16 * 4 + rr;
                eb[k * C_N + c] = acc[k2][cc][rr];
            }
        }
    }
    // ---- theta_sum: per-thread partials -> LDS (reuse xcT_s) -> 64-thread reduce ----
    #pragma unroll
    for (int j = 0; j < 4; ++j)
        xcT_s[(r16 * 4 + j) * (NT + 1) + sm_n] = ts_acc[j];
    __syncthreads();
    if (tid < K_N) {
        float ts = 0.f;
        #pragma unroll 8
        for (int n = 0; n < NT; ++n) ts += xcT_s[tid * (NT + 1) + n];
        ws_ts[gid * K_N + tid] = ts;
    }
}

__global__ void se_reduce_kernel(const float* __restrict__ ws_enc,
                                 const float* __restrict__ ws_ts,
                                 const float* __restrict__ clusters,
                                 float* __restrict__ out) {
    int tid = blockIdx.x * 256 + threadIdx.x;   // 131072 threads: (b,k,c4)
    int c4 = tid & 63;
    int k = (tid >> 6) & 63;
    int b = tid >> 12;
    float4 a = {0.f, 0.f, 0.f, 0.f};
    size_t base = (size_t)(b * 16) * (K_N * C_N) + k * C_N + c4 * 4;
    #pragma unroll
    for (int p = 0; p < 16; ++p) {
        float4 v = *(const float4*)(ws_enc + base + (size_t)p * (K_N * C_N));
        a.x += v.x; a.y += v.y; a.z += v.z; a.w += v.w;
    }
    float ts = 0.f;
    #pragma unroll
    for (int p = 0; p < 16; ++p) ts += ws_ts[(b * 16 + p) * K_N + k];
    float4 cl = *(const float4*)(clusters + k * C_N + c4 * 4);
    float4 o;
    o.x = a.x - ts * cl.x;
    o.y = a.y - ts * cl.y;
    o.z = a.z - ts * cl.z;
    o.w = a.w - ts * cl.w;
    *(float4*)(out + (size_t)(b * K_N + k) * C_N + c4 * 4) = o;
}

extern "C" void kernel_launch(void* const* d_in, const int* in_sizes, int n_in,
                              void* d_out, int out_size, void* d_ws, size_t ws_size,
                              hipStream_t stream) {
    const float* x        = (const float*)d_in[0];
    const float* clusters = (const float*)d_in[1];
    const float* scale    = (const float*)d_in[2];
    float* out    = (float*)d_out;
    float* ws_enc = (float*)d_ws;                                  // 512*64*256 f32 = 32 MB
    float* ws_ts  = ws_enc + (size_t)NBLOCKS * K_N * C_N;          // + 512*64 f32

    se_main_kernel<<<NBLOCKS, NTHREADS, 0, stream>>>(x, clusters, scale, ws_enc, ws_ts);
    se_reduce_kernel<<<(B_N * K_N * 64) / 256, 256, 0, stream>>>(ws_enc, ws_ts, clusters, out);
}

// Round 7
// 238.239 us; speedup vs baseline: 1.4582x; 1.1436x over previous
//
#include <hip/hip_runtime.h>

#define B_N 32
#define C_N 256
#define HW_N 4096
#define K_N 64
#define NT 32              // positions per subtile
#define SUBT 8             // subtiles per block -> 256 positions/block
#define NTHREADS 512
#define NBLOCKS 512        // 32 batches x 16 chunks -> 2 blocks/CU
#define XROW 40            // padded row (u16 units) for x_s

typedef __attribute__((ext_vector_type(8))) short short8;
typedef __attribute__((ext_vector_type(4))) unsigned short ushort4v;
typedef __attribute__((ext_vector_type(4))) float f32x4;

__device__ __forceinline__ unsigned short f2bf(float f) {
    unsigned int u = __builtin_bit_cast(unsigned int, f);
    u = (u + 0x7FFFu + ((u >> 16) & 1u)) >> 16;   // RNE
    return (unsigned short)u;
}

// xT_s [NT][C] c-innermost; XOR swizzle: mm1 A-frag reads and staging
// transpose-writes both land <=2-way
__device__ __forceinline__ int xts_idx(int n, int c) {
    int sw = (n & 7) ^ ((n >> 3) & 3);
    return (n * C_N + c) ^ (sw << 3);
}
// thT_s [K][NT] n-innermost; mask hits n-bits 3..4 ONLY -> b128 fragment
// reads stay 16B-aligned + contiguous (bit-2 XOR variant NaN'd in round 4).
__device__ __forceinline__ int tht_idx(int k, int n) {
    int sw = (k & 3) ^ ((k >> 2) & 3);
    return (k * NT + n) ^ (sw << 3);
}

// Register-tier fit: round-5/6 showed the allocator pins arch-VGPR=64 and
// spills cb[8] (32 regs -> +34MB scratch writes, reloads on mm1 critical
// path). cb[4] (16 regs) + per-wave c-half fits the 64-reg tier.
__launch_bounds__(NTHREADS, 4)
__global__ void se_main_kernel(const float* __restrict__ x,
                               const float* __restrict__ clusters,
                               const float* __restrict__ scale,
                               float* __restrict__ ws_enc,
                               float* __restrict__ ws_ts) {
    __shared__ unsigned short x_s[C_N * XROW];    // 20480 B  [C][40] n-innermost, pad-40
    __shared__ unsigned short xT_s[NT * C_N];     // 16384 B  [NT][C] c-innermost, swizzled
    __shared__ float xcT2_s[2][K_N * (NT + 1)];   // 16896 B  [half][K][NT+1] mm1 partials
    __shared__ unsigned short thT_s[K_N * NT];    //  4096 B  [K][NT] swizzled
    __shared__ float xsqp_s[8 * NT];              //  1024 B  per-wave x_sq partials
    __shared__ float csq_s[K_N];                  //   256 B
    __shared__ float scl2_s[K_N];                 //   256 B   total 59392 B -> 2 blocks/CU

    const int tid = threadIdx.x;
    const int w = tid >> 6;         // wave 0..7
    const int l = tid & 63;
    const int gid = blockIdx.x;
    const int b = gid >> 4;
    const int chunk = gid & 15;
    const int r16 = l & 15, g16 = l >> 4;
    const int u = l >> 3;           // staging c sub-row
    const int ng = l & 7;           // staging n-group (4 consecutive n)
    // softmax mapping: 16 lanes (r16) per position, each lane 4 k's
    const int sm_n = w * 4 + g16;   // position 0..31

    // ---- c_sq and scale*log2(e), fp32 exact ----
    if (tid < K_N) {
        const float4* cr = (const float4*)(clusters + tid * C_N);
        float ss = 0.f;
        #pragma unroll 8
        for (int i = 0; i < C_N / 4; ++i) {
            float4 v = cr[i];
            ss += v.x * v.x + v.y * v.y + v.z * v.z + v.w * v.w;
        }
        csq_s[tid] = ss;
        scl2_s[tid] = scale[tid] * 1.4426950408889634f;
    }

    // ---- mm1 clusters B-fragments: wave w owns k-tile kt AND c-half ch ----
    const int kt = w >> 1;          // 0..3
    const int ch = w & 1;           // c-half: [ch*128, ch*128+128)
    short8 cb[4];                   // 16 VGPRs (was 32 -> spilled)
    #pragma unroll
    for (int st = 0; st < 4; ++st) {
        int k = kt * 16 + r16;
        int c0 = ch * 128 + st * 32 + g16 * 8;
        const float* p = clusters + k * C_N + c0;
        short8 v;
        #pragma unroll
        for (int j = 0; j < 8; ++j) v[j] = (short)f2bf(p[j]);
        cb[st] = v;
    }

    // mm2: enc(K x C); wave w owns c-tiles {2w,2w+1}, all 4 k-tiles
    const int ct0 = w * 2;
    f32x4 acc[4][2];
    #pragma unroll
    for (int a = 0; a < 4; ++a)
        #pragma unroll
        for (int cc = 0; cc < 2; ++cc) acc[a][cc] = (f32x4)0.f;
    float ts_acc[4] = {0.f, 0.f, 0.f, 0.f};   // per-thread theta partials (k=r16*4+j, own positions)

    // ---- prefetch subtile 0 into registers ----
    const size_t xbase = (size_t)b * C_N * HW_N + chunk * (SUBT * NT);
    float4 pva[4];
    #pragma unroll
    for (int p = 0; p < 4; ++p)
        pva[p] = *(const float4*)(x + xbase + (size_t)(w * 8 + u + p * 64) * HW_N + ng * 4);

    for (int s = 0; s < SUBT; ++s) {
        __syncthreads();  // BAR0: x_s/xT_s/thT free (prev mm2 done)

        // ---- convert prefetched regs -> bf16 LDS (both layouts), x_sq partials ----
        float xsq4[4] = {0.f, 0.f, 0.f, 0.f};
        #pragma unroll
        for (int p = 0; p < 4; ++p) {
            int c = w * 8 + u + p * 64;
            float v0 = pva[p].x, v1 = pva[p].y, v2 = pva[p].z, v3 = pva[p].w;
            xsq4[0] += v0 * v0; xsq4[1] += v1 * v1;
            xsq4[2] += v2 * v2; xsq4[3] += v3 * v3;
            unsigned short b0 = f2bf(v0), b1 = f2bf(v1), b2 = f2bf(v2), b3 = f2bf(v3);
            ushort4v pk = {b0, b1, b2, b3};
            *(ushort4v*)&x_s[c * XROW + ng * 4] = pk;       // b64 write, ~2-way max
            xT_s[xts_idx(ng * 4 + 0, c)] = b0;              // swizzled transpose
            xT_s[xts_idx(ng * 4 + 1, c)] = b1;
            xT_s[xts_idx(ng * 4 + 2, c)] = b2;
            xT_s[xts_idx(ng * 4 + 3, c)] = b3;
        }
        // ---- issue next subtile's loads NOW; latency hides under mm1+softmax+mm2 ----
        if (s + 1 < SUBT) {
            #pragma unroll
            for (int p = 0; p < 4; ++p)
                pva[p] = *(const float4*)(x + xbase + (size_t)(w * 8 + u + p * 64) * HW_N
                                          + (s + 1) * NT + ng * 4);
        }
        // x_sq reduce over u (lane bits 3..5), fp32 exact
        #pragma unroll
        for (int i = 0; i < 4; ++i) {
            float t = xsq4[i];
            t += __shfl_xor(t, 8, 64);
            t += __shfl_xor(t, 16, 64);
            t += __shfl_xor(t, 32, 64);
            xsq4[i] = t;
        }
        if (u == 0) {
            #pragma unroll
            for (int i = 0; i < 4; ++i) xsqp_s[w * NT + ng * 4 + i] = xsq4[i];
        }
        __syncthreads(); // BAR1: xT_s + xsq partials ready

        // ---- mm1: wave computes BOTH n-tiles over its c-half; D[n][k] partial ----
        {
            f32x4 a0 = (f32x4)0.f, a1 = (f32x4)0.f;
            #pragma unroll
            for (int st = 0; st < 4; ++st) {
                int c0 = ch * 128 + st * 32 + g16 * 8;
                short8 af0 = *(const short8*)&xT_s[xts_idx(r16, c0)];
                short8 af1 = *(const short8*)&xT_s[xts_idx(16 + r16, c0)];
                a0 = __builtin_amdgcn_mfma_f32_16x16x32_bf16(af0, cb[st], a0, 0, 0, 0);
                a1 = __builtin_amdgcn_mfma_f32_16x16x32_bf16(af1, cb[st], a1, 0, 0, 0);
            }
            #pragma unroll
            for (int rr = 0; rr < 4; ++rr) {
                xcT2_s[ch][(kt * 16 + r16) * (NT + 1) + g16 * 4 + rr] = a0[rr];
                xcT2_s[ch][(kt * 16 + r16) * (NT + 1) + 16 + g16 * 4 + rr] = a1[rr];
            }
        }
        __syncthreads(); // BAR2: xcT halves ready

        // ---- softmax, fully in-wave: position sm_n, lane r16 owns k=r16*4+j ----
        float xsq = 0.f;
        #pragma unroll
        for (int ww = 0; ww < 8; ++ww) xsq += xsqp_s[ww * NT + sm_n];
        float lg[4], m8 = -1e30f;
        #pragma unroll
        for (int j = 0; j < 4; ++j) {
            int k = r16 * 4 + j;
            float xc = xcT2_s[0][k * (NT + 1) + sm_n] + xcT2_s[1][k * (NT + 1) + sm_n];
            lg[j] = scl2_s[k] * (xsq - 2.f * xc + csq_s[k]);   // log2 domain
            m8 = fmaxf(m8, lg[j]);
        }
        // global max over 64 k = 16-lane butterfly (lane bits 0-3)
        m8 = fmaxf(m8, __shfl_xor(m8, 1, 64));
        m8 = fmaxf(m8, __shfl_xor(m8, 2, 64));
        m8 = fmaxf(m8, __shfl_xor(m8, 4, 64));
        m8 = fmaxf(m8, __shfl_xor(m8, 8, 64));
        float e4[4], s8 = 0.f;
        #pragma unroll
        for (int j = 0; j < 4; ++j) { e4[j] = exp2f(lg[j] - m8); s8 += e4[j]; }
        s8 += __shfl_xor(s8, 1, 64);
        s8 += __shfl_xor(s8, 2, 64);
        s8 += __shfl_xor(s8, 4, 64);
        s8 += __shfl_xor(s8, 8, 64);
        float fsc = __fdividef(1.0f, s8);
        #pragma unroll
        for (int j = 0; j < 4; ++j) {
            float th = e4[j] * fsc;
            thT_s[tht_idx(r16 * 4 + j, sm_n)] = f2bf(th);
            ts_acc[j] += th;                 // deferred theta_sum (reduced once at end)
        }
        __syncthreads(); // BAR3: thT ready

        // ---- mm2: acc[k-tile][c-tile] += thetaT * xf (single K=32 step) ----
        short8 av[4];
        #pragma unroll
        for (int k2 = 0; k2 < 4; ++k2)
            av[k2] = *(const short8*)&thT_s[tht_idx(k2 * 16 + r16, g16 * 8)];
        #pragma unroll
        for (int cc = 0; cc < 2; ++cc) {
            short8 bv = *(const short8*)&x_s[((ct0 + cc) * 16 + r16) * XROW + g16 * 8];
            #pragma unroll
            for (int k2 = 0; k2 < 4; ++k2)
                acc[k2][cc] = __builtin_amdgcn_mfma_f32_16x16x32_bf16(av[k2], bv, acc[k2][cc], 0, 0, 0);
        }
    }

    // ---- write per-block enc partials ----
    float* eb = ws_enc + (size_t)gid * (K_N * C_N);
    #pragma unroll
    for (int k2 = 0; k2 < 4; ++k2) {
        #pragma unroll
        for (int cc = 0; cc < 2; ++cc) {
            int c = (ct0 + cc) * 16 + r16;
            #pragma unroll
            for (int rr = 0; rr < 4; ++rr) {
                int k = k2 * 16 + g16 * 4 + rr;
                eb[k * C_N + c] = acc[k2][cc][rr];
            }
        }
    }
    // ---- theta_sum: per-thread partials -> LDS (reuse xcT2_s[0]) -> 64-thread reduce ----
    #pragma unroll
    for (int j = 0; j < 4; ++j)
        xcT2_s[0][(r16 * 4 + j) * (NT + 1) + sm_n] = ts_acc[j];
    __syncthreads();
    if (tid < K_N) {
        float ts = 0.f;
        #pragma unroll 8
        for (int n = 0; n < NT; ++n) ts += xcT2_s[0][tid * (NT + 1) + n];
        ws_ts[gid * K_N + tid] = ts;
    }
}

__global__ void se_reduce_kernel(const float* __restrict__ ws_enc,
                                 const float* __restrict__ ws_ts,
                                 const float* __restrict__ clusters,
                                 float* __restrict__ out) {
    int tid = blockIdx.x * 256 + threadIdx.x;   // 131072 threads: (b,k,c4)
    int c4 = tid & 63;
    int k = (tid >> 6) & 63;
    int b = tid >> 12;
    float4 a = {0.f, 0.f, 0.f, 0.f};
    size_t base = (size_t)(b * 16) * (K_N * C_N) + k * C_N + c4 * 4;
    #pragma unroll
    for (int p = 0; p < 16; ++p) {
        float4 v = *(const float4*)(ws_enc + base + (size_t)p * (K_N * C_N));
        a.x += v.x; a.y += v.y; a.z += v.z; a.w += v.w;
    }
    float ts = 0.f;
    #pragma unroll
    for (int p = 0; p < 16; ++p) ts += ws_ts[(b * 16 + p) * K_N + k];
    float4 cl = *(const float4*)(clusters + k * C_N + c4 * 4);
    float4 o;
    o.x = a.x - ts * cl.x;
    o.y = a.y - ts * cl.y;
    o.z = a.z - ts * cl.z;
    o.w = a.w - ts * cl.w;
    *(float4*)(out + (size_t)(b * K_N + k) * C_N + c4 * 4) = o;
}

extern "C" void kernel_launch(void* const* d_in, const int* in_sizes, int n_in,
                              void* d_out, int out_size, void* d_ws, size_t ws_size,
                              hipStream_t stream) {
    const float* x        = (const float*)d_in[0];
    const float* clusters = (const float*)d_in[1];
    const float* scale    = (const float*)d_in[2];
    float* out    = (float*)d_out;
    float* ws_enc = (float*)d_ws;                                  // 512*64*256 f32 = 32 MB
    float* ws_ts  = ws_enc + (size_t)NBLOCKS * K_N * C_N;          // + 512*64 f32

    se_main_kernel<<<NBLOCKS, NTHREADS, 0, stream>>>(x, clusters, scale, ws_enc, ws_ts);
    se_reduce_kernel<<<(B_N * K_N * 64) / 256, 256, 0, stream>>>(ws_enc, ws_ts, clusters, out);
}